// Round 24
// baseline (674.263 us; speedup 1.0000x reference)
//
#include <hip/hip_runtime.h>

#define DEV static __device__ __forceinline__

using bf16x8 = __attribute__((ext_vector_type(8))) short;   // 8 bf16 (4 VGPRs)
using f32x4  = __attribute__((ext_vector_type(4))) float;

DEV float sqdist(float dx, float dy, float dz) {
    // ((dx*dx + dy*dy) + dz*dz) with no FMA contraction — must match numpy f32
    return __fadd_rn(__fadd_rn(__fmul_rn(dx, dx), __fmul_rn(dy, dy)), __fmul_rn(dz, dz));
}

DEV void fma4(float4& acc, float h, const float4& w) {
    acc.x = fmaf(h, w.x, acc.x); acc.y = fmaf(h, w.y, acc.y);
    acc.z = fmaf(h, w.z, acc.z); acc.w = fmaf(h, w.w, acc.w);
}

DEV unsigned short f2bf_rne(float f) {   // fp32 -> bf16, round-nearest-even
    unsigned u = __builtin_bit_cast(unsigned, f);
    return (unsigned short)((u + 0x7FFFu + ((u >> 16) & 1u)) >> 16);
}

// ---- weight pre-swizzle section: fp32 W[K][C] -> bf16 fragment layout ----
// out[((nt*KB+kb)*64+lane)*8 + j] = bf16(W[kb*32+(lane>>4)*8+j][nt*16+(lane&15)])
template<int KSRC, int KB, int C>
DEV void wswz_sec(const float* __restrict__ W, unsigned short* __restrict__ out,
                  int idx0, int stride)
{
    constexpr int NT = C / 16;
    constexpr int TOTAL = NT * KB * 64 * 8;
    for (int idx = idx0; idx < TOTAL; idx += stride) {
        const int j    = idx & 7;
        const int lane = (idx >> 3) & 63;
        const int fb   = idx >> 9;          // nt*KB + kb
        const int kb   = fb % KB, nt = fb / KB;
        const int k    = kb * 32 + (lane >> 4) * 8 + j;
        const int c    = nt * 16 + (lane & 15);
        const float v  = (k < KSRC) ? W[(size_t)k * C + c] : 0.f;
        out[idx] = f2bf_rne(v);
    }
}

// ---- argmax combine steps (value desc, index asc on ties) ----
template<int CTRL>
DEV int dpp_mov(int v) {
    return __builtin_amdgcn_update_dpp(v, v, CTRL, 0xF, 0xF, false);
}
template<int CTRL>
DEV void red_step_dpp(float& bv, int& bi) {
    float ov = __builtin_bit_cast(float, dpp_mov<CTRL>(__builtin_bit_cast(int, bv)));
    int   oi = dpp_mov<CTRL>(bi);
    if (ov > bv || (ov == bv && oi < bi)) { bv = ov; bi = oi; }
}
// full 64-lane argmax; result valid in lane 63
DEV void wave_argmax(float& bv, int& bi) {
    red_step_dpp<0xB1>(bv, bi);    // quad_perm xor 1
    red_step_dpp<0x4E>(bv, bi);    // quad_perm xor 2
    red_step_dpp<0x141>(bv, bi);   // row_half_mirror (xor 4)
    red_step_dpp<0x140>(bv, bi);   // row_mirror (xor 8)
    red_step_dpp<0x142>(bv, bi);   // row_bcast15
    red_step_dpp<0x143>(bv, bi);   // row_bcast31 -> lane 63 has full result
}

// ---- single-wave FPS over LDS points (no barriers) ----
template<int N, int NPOINT>
DEV void fps_wave64(const float4* pts, float* sout, int lane) {
    constexpr int K = (N + 63) / 64;
    float rx[K], ry[K], rz[K], d[K];
#pragma unroll
    for (int k = 0; k < K; ++k) {
        const float4 c = pts[lane + k * 64];
        rx[k] = c.x; ry[k] = c.y; rz[k] = c.z; d[k] = 1e10f;
    }
    const float4 c0 = pts[0];
    float cx = c0.x, cy = c0.y, cz = c0.z;
    for (int s = 0; s < NPOINT; ++s) {
        if (lane == 0) { sout[s * 3 + 0] = cx; sout[s * 3 + 1] = cy; sout[s * 3 + 2] = cz; }
        float bestv = -1.0f; int besti = 0x7fffffff;
#pragma unroll
        for (int k = 0; k < K; ++k) {
            float d2 = sqdist(rx[k] - cx, ry[k] - cy, rz[k] - cz);
            d[k] = fminf(d[k], d2);
            if (d[k] > bestv) { bestv = d[k]; besti = lane + k * 64; }
        }
        wave_argmax(bestv, besti);
        const int far = __builtin_amdgcn_readlane(besti, 63);
        const float4 c = pts[far];
        cx = c.x; cy = c.y; cz = c.z;
    }
}

// ---- FPS device body (all 3 stages, 4-wave measured-floor config) ----
DEV void fps_body(const float* __restrict__ pc, int b, int tid,
                  float* __restrict__ nxyz1, float* __restrict__ nxyz2,
                  float* __restrict__ nxyz3)
{
    constexpr int N1 = 4096, NP1 = 256, NP2 = 64, NP3 = 16, T = 256, NW = T / 64;
    constexpr int K = N1 / T;
    __shared__ float4 pxyz[N1];
    __shared__ float  sout1[NP1 * 3];
    __shared__ float  sout2[NP2 * 3];
    __shared__ float  sout3[NP3 * 3];
    __shared__ float  rv[2][NW];
    __shared__ int    ri[2][NW];

    const int w = tid >> 6, lane = tid & 63;
    const float* base = pc + (size_t)b * N1 * 6;

    float rx[K], ry[K], rz[K], d[K];
#pragma unroll
    for (int k = 0; k < K; ++k) {
        const int p = tid + k * T;
        const float x = base[p * 6 + 0];
        const float y = base[p * 6 + 1];
        const float z = base[p * 6 + 2];
        pxyz[p] = make_float4(x, y, z, 0.f);
        rx[k] = x; ry[k] = y; rz[k] = z;
        d[k] = 1e10f;
    }
    __syncthreads();

    // ---- stage 1 ----
    {
        const float4 c0 = pxyz[0];
        float cx = c0.x, cy = c0.y, cz = c0.z;
        for (int s = 0; s < NP1; ++s) {
            if (tid == 0) { sout1[s * 3 + 0] = cx; sout1[s * 3 + 1] = cy; sout1[s * 3 + 2] = cz; }
            float bestv = -1.0f; int besti = 0x7fffffff;
#pragma unroll
            for (int k = 0; k < K; ++k) {
                float d2 = sqdist(rx[k] - cx, ry[k] - cy, rz[k] - cz);
                d[k] = fminf(d[k], d2);
                if (d[k] > bestv) { bestv = d[k]; besti = tid + k * T; }  // k asc => lowest p
            }
            wave_argmax(bestv, besti);

            const int par = s & 1;
            if (lane == 63) { rv[par][w] = bestv; ri[par][w] = besti; }
            __syncthreads();
            float bvv = rv[par][0]; int bii = ri[par][0];
#pragma unroll
            for (int q = 1; q < NW; ++q) {
                const float qv = rv[par][q]; const int qi = ri[par][q];
                if (qv > bvv || (qv == bvv && qi < bii)) { bvv = qv; bii = qi; }
            }
            const float4 c = pxyz[bii];
            cx = c.x; cy = c.y; cz = c.z;
        }
    }

    // ---- stages 2 + 3 on wave 0 ----
    if (w == 0) {
        for (int i = lane; i < NP1; i += 64)
            pxyz[i] = make_float4(sout1[i * 3 + 0], sout1[i * 3 + 1], sout1[i * 3 + 2], 0.f);
        fps_wave64<NP1, NP2>(pxyz, sout2, lane);
        for (int i = lane; i < NP2; i += 64)
            pxyz[i] = make_float4(sout2[i * 3 + 0], sout2[i * 3 + 1], sout2[i * 3 + 2], 0.f);
        fps_wave64<NP2, NP3>(pxyz, sout3, lane);
    }
    __syncthreads();

    float* o1 = nxyz1 + (size_t)b * NP1 * 3;
    for (int i = tid; i < NP1 * 3; i += T) o1[i] = sout1[i];
    float* o2 = nxyz2 + (size_t)b * NP2 * 3;
    if (tid < NP2 * 3) o2[tid] = sout2[tid];
    float* o3 = nxyz3 + (size_t)b * NP3 * 3;
    if (tid < NP3 * 3) o3[tid] = sout3[tid];
}

// ---- merged launch: blocks 0-31 run FPS; blocks 32-159 run weight swizzle ----
__global__ __launch_bounds__(256)
void fps_wswz_kernel(const float* __restrict__ pc,
                     float* __restrict__ nxyz1, float* __restrict__ nxyz2,
                     float* __restrict__ nxyz3,
                     const float* w1a, unsigned short* o1a,
                     const float* w1b, unsigned short* o1b,
                     const float* w2a, unsigned short* o2a,
                     const float* w2b, unsigned short* o2b,
                     const float* w3a, unsigned short* o3a,
                     const float* w3b, unsigned short* o3b,
                     const float* w4a, unsigned short* o4a,
                     const float* w4b, unsigned short* o4b)
{
    if (blockIdx.x < 32) {
        fps_body(pc, blockIdx.x, threadIdx.x, nxyz1, nxyz2, nxyz3);
    } else {
        const int idx0   = (blockIdx.x - 32) * 256 + threadIdx.x;
        const int stride = 128 * 256;
        wswz_sec<9,   1,  64 >(w1a, o1a, idx0, stride);
        wswz_sec<64,  2,  128>(w1b, o1b, idx0, stride);
        wswz_sec<131, 5,  128>(w2a, o2a, idx0, stride);
        wswz_sec<128, 4,  256>(w2b, o2b, idx0, stride);
        wswz_sec<259, 9,  256>(w3a, o3a, idx0, stride);
        wswz_sec<256, 8,  512>(w3b, o3b, idx0, stride);
        wswz_sec<515, 17, 512>(w4a, o4a, idx0, stride);
        wswz_sec<512, 16, 1024>(w4b, o4b, idx0, stride);
    }
}

// ---------------- Grouped 2-layer MLP + maxpool, FULL MFMA, inline ball query ----
// Both layers on mfma_f32_16x16x32_bf16; W1s/W2s pre-swizzled bf16 fragments.
// MODE 0: stage1 gather (xyz stride 6, feats = pc permuted [3:6]++[0:3]).
// MODE 1: mid stages (xyz stride 3, feats array).
// MODE 2: head — direct rows, fused maxpool, then fc1/fc2/bn in-block.
// For MODE 0/1 the ball query (identical algorithm/inputs to the old bq kernel)
// runs on wave 0 into LDS gix — no gidx global round-trip, no separate launch.
template<int NS, int CIN, int C1, int C2, int NSRC, int MODE>
__global__ __launch_bounds__(256)
void sa_mlp_mfma_kernel(const float* __restrict__ sxyz, const float* __restrict__ sfeat,
                        const float* __restrict__ newxyz, float r2,
                        const unsigned short* __restrict__ W1s, const float* __restrict__ B1v,
                        const unsigned short* __restrict__ W2s, const float* __restrict__ B2v,
                        float* __restrict__ outf, int S,
                        const float* __restrict__ fc1w = nullptr, const float* __restrict__ fc1b = nullptr,
                        const float* __restrict__ fc2w = nullptr, const float* __restrict__ fc2b = nullptr,
                        const float* __restrict__ gamma = nullptr, const float* __restrict__ beta = nullptr)
{
    constexpr int T    = 256;
    constexpr int KP   = ((CIN + 31) / 32) * 32;   // K padded
    constexpr int LDXB = KP + 8;                   // bf16 x row stride (16B mult)
    constexpr int KBA  = KP / 32;                  // phase-A K-blocks
    constexpr int NMT  = NS / 16;                  // M-tiles
    constexpr int NTA  = C1 / 16 / 4;              // phase-A N-tiles per wave
    constexpr int LDHB = C1 + 8;                   // bf16 h1 row stride
    constexpr int KBB  = C1 / 32;                  // phase-B K-blocks
    constexpr int NTB  = C2 / 16 / 4;              // phase-B N-tiles per wave
    constexpr int CF   = CIN - 3;
    constexpr int XS   = (MODE == 0) ? 6 : 3;
    static_assert(NS % 16 == 0 && C1 % 64 == 0 && C2 % 64 == 0, "");

    __shared__ __align__(16) unsigned short xb[NS * LDXB];
    __shared__ __align__(16) unsigned short h1b[NS * LDHB];
    __shared__ int gix[NS];
    __shared__ float gmS[(MODE == 2) ? C2 : 4];    // fused-head: pooled features
    __shared__ float g1S[(MODE == 2) ? 1024 : 4];  // fused-head: fc1 output

    const int g   = blockIdx.x;
    const int b   = g / S;
    const int tid = threadIdx.x;
    const int w    = tid >> 6;
    const int lane = tid & 63;
    const int lr   = lane & 15;
    const int lg   = lane >> 4;

    float ctr0 = 0.f, ctr1 = 0.f, ctr2 = 0.f;
    if constexpr (MODE != 2) {
        ctr0 = newxyz[(size_t)g * 3 + 0];
        ctr1 = newxyz[(size_t)g * 3 + 1];
        ctr2 = newxyz[(size_t)g * 3 + 2];
        // ---- inline ball query (wave 0): identical algorithm to old bq kernel ----
        if (w == 0) {
            const float* base = sxyz + (size_t)b * NSRC * XS;
            int count = 0, first = NSRC - 1;
            constexpr int NCH = (NSRC + 63) / 64;
            for (int ch = 0; ch < NCH; ++ch) {
                const int p = ch * 64 + lane;
                bool pred = false;
                if (NSRC % 64 == 0 || p < NSRC) {
                    const float dx = base[p * XS + 0] - ctr0;
                    const float dy = base[p * XS + 1] - ctr1;
                    const float dz = base[p * XS + 2] - ctr2;
                    pred = sqdist(dx, dy, dz) < r2;
                }
                unsigned long long m = __ballot(pred);
                if (m) {
                    if (count == 0) first = ch * 64 + __builtin_ctzll(m);
                    int pos = count + __popcll(m & ((1ull << lane) - 1ull));
                    if (pred && pos < NS) gix[pos] = p;
                    count += __popcll(m);
                    if (count >= NS) break;
                }
            }
            if (count > NS) count = NS;
            for (int pos = count + lane; pos < NS; pos += 64) gix[pos] = first;
        }
        __syncthreads();
    }

    // ---- gather full input as bf16 (rel-xyz in fp32, then RNE; pad = 0) ----
    for (int idx = tid; idx < NS * KP; idx += T) {
        const int p = idx / KP, k = idx - p * KP;
        float v = 0.f;
        if (k < CIN) {
            if constexpr (MODE == 2) {
                v = (k < 3) ? sxyz[((size_t)g * NS + p) * 3 + k]
                            : sfeat[((size_t)g * NS + p) * CF + (k - 3)];
            } else if constexpr (MODE == 0) {
                const int gi = gix[p];
                if (k < 3) {
                    const float c = (k == 0) ? ctr0 : ((k == 1) ? ctr1 : ctr2);
                    v = sxyz[((size_t)b * NSRC + gi) * 6 + k] - c;
                } else {
                    const int j2 = k - 3;   // feats = [pc[:,3:6], pc[:,0:3]]
                    v = sfeat[((size_t)b * NSRC + gi) * 6 + (j2 < 3 ? 3 + j2 : j2 - 3)];
                }
            } else {
                const int gi = gix[p];
                if (k < 3) {
                    const float c = (k == 0) ? ctr0 : ((k == 1) ? ctr1 : ctr2);
                    v = sxyz[((size_t)b * NSRC + gi) * 3 + k] - c;
                } else {
                    v = sfeat[((size_t)b * NSRC + gi) * CF + (k - 3)];
                }
            }
        }
        xb[(size_t)p * LDXB + k] = f2bf_rne(v);
    }
    __syncthreads();

    // ---- Phase A: h1 = relu(x @ W1 + b1) via MFMA ----
    {
        bf16x8 af[NMT][KBA];
#pragma unroll
        for (int mt = 0; mt < NMT; ++mt)
#pragma unroll
            for (int kb = 0; kb < KBA; ++kb)
                af[mt][kb] = *(const bf16x8*)&xb[(size_t)(mt * 16 + lr) * LDXB + kb * 32 + lg * 8];

#pragma unroll
        for (int q = 0; q < NTA; ++q) {
            const int nt = w * NTA + q;
            const int c  = nt * 16 + lr;
            bf16x8 bfr[KBA];
#pragma unroll
            for (int kb = 0; kb < KBA; ++kb)
                bfr[kb] = *(const bf16x8*)&W1s[(size_t)((nt * KBA + kb) * 64 + lane) * 8];
            const float bb = B1v[c];
#pragma unroll
            for (int mt = 0; mt < NMT; ++mt) {
                f32x4 ac = {bb, bb, bb, bb};
#pragma unroll
                for (int kb = 0; kb < KBA; ++kb)
                    ac = __builtin_amdgcn_mfma_f32_16x16x32_bf16(af[mt][kb], bfr[kb], ac, 0, 0, 0);
#pragma unroll
                for (int i = 0; i < 4; ++i) {
                    const int row = mt * 16 + lg * 4 + i;
                    h1b[(size_t)row * LDHB + c] = f2bf_rne(fmaxf(ac[i], 0.f));
                }
            }
        }
    }
    __syncthreads();

    // ---- Phase B: out = maxpool_p (h1 @ W2 + b2) via MFMA ----
    {
        bf16x8 af[NMT][KBB];
#pragma unroll
        for (int mt = 0; mt < NMT; ++mt)
#pragma unroll
            for (int kb = 0; kb < KBB; ++kb)
                af[mt][kb] = *(const bf16x8*)&h1b[(size_t)(mt * 16 + lr) * LDHB + kb * 32 + lg * 8];

#pragma unroll
        for (int q = 0; q < NTB; ++q) {
            const int nt = w * NTB + q;
            const int c  = nt * 16 + lr;
            bf16x8 bfr[KBB];
#pragma unroll
            for (int kb = 0; kb < KBB; ++kb)
                bfr[kb] = *(const bf16x8*)&W2s[(size_t)((nt * KBB + kb) * 64 + lane) * 8];
            const float bb = B2v[c];
            float colmax = 0.f;   // relu >= 0
#pragma unroll
            for (int mt = 0; mt < NMT; ++mt) {
                f32x4 ac = {bb, bb, bb, bb};
#pragma unroll
                for (int kb = 0; kb < KBB; ++kb)
                    ac = __builtin_amdgcn_mfma_f32_16x16x32_bf16(af[mt][kb], bfr[kb], ac, 0, 0, 0);
                float pm = fmaxf(fmaxf(ac[0], ac[1]), fmaxf(ac[2], ac[3]));
                pm = fmaxf(pm, __shfl_xor(pm, 16));
                pm = fmaxf(pm, __shfl_xor(pm, 32));
                colmax = fmaxf(colmax, pm);
            }
            if constexpr (MODE == 2) {
                if (lg == 0) gmS[c] = colmax;
            } else {
                if (lg == 0) outf[(size_t)g * C2 + c] = colmax;
            }
        }
    }

    // ---- fused head tail: fc1(relu) -> fc2 -> bn-ish (MODE 2 only) ----
    if constexpr (MODE == 2) {
        __syncthreads();
        {
            const int c0 = tid * 4;
            float4 a = *(const float4*)&fc1b[c0];
#pragma unroll 4
            for (int k = 0; k < 1024; ++k) {
                const float4 ww = *(const float4*)&fc1w[(size_t)k * 1024 + c0];
                fma4(a, gmS[k], ww);
            }
            g1S[c0 + 0] = fmaxf(a.x, 0.f); g1S[c0 + 1] = fmaxf(a.y, 0.f);
            g1S[c0 + 2] = fmaxf(a.z, 0.f); g1S[c0 + 3] = fmaxf(a.w, 0.f);
        }
        __syncthreads();
        if (tid < 128) {
            const float s = sqrtf(1.00001f);
            const int c = tid;
            float a = fc2b[c];
#pragma unroll 4
            for (int k = 0; k < 1024; ++k) a = fmaf(g1S[k], fc2w[(size_t)k * 128 + c], a);
            outf[(size_t)g * 128 + c] = (a / s) * gamma[c] + beta[c];
        }
    }
}

// ---------------------------------------------------------------------------
extern "C" void kernel_launch(void* const* d_in, const int* in_sizes, int n_in,
                              void* d_out, int out_size, void* d_ws, size_t ws_size,
                              hipStream_t stream)
{
    const float* pc   = (const float*)d_in[0];
    const float* w1a  = (const float*)d_in[1];  const float* b1a = (const float*)d_in[2];
    const float* w1b  = (const float*)d_in[3];  const float* b1b = (const float*)d_in[4];
    const float* w2a  = (const float*)d_in[5];  const float* b2a = (const float*)d_in[6];
    const float* w2b  = (const float*)d_in[7];  const float* b2b = (const float*)d_in[8];
    const float* w3a  = (const float*)d_in[9];  const float* b3a = (const float*)d_in[10];
    const float* w3b  = (const float*)d_in[11]; const float* b3b = (const float*)d_in[12];
    const float* w4a  = (const float*)d_in[13]; const float* b4a = (const float*)d_in[14];
    const float* w4b  = (const float*)d_in[15]; const float* b4b = (const float*)d_in[16];
    const float* fc1w = (const float*)d_in[17]; const float* fc1b = (const float*)d_in[18];
    const float* fc2w = (const float*)d_in[19]; const float* fc2b = (const float*)d_in[20];
    const float* gam  = (const float*)d_in[21]; const float* bet  = (const float*)d_in[22];
    float* out = (float*)d_out;

    char* ws = (char*)d_ws;
    size_t off = 0;
    auto alloc = [&](size_t bytes) -> void* {
        void* p = ws + off;
        off = (off + bytes + 255) & ~(size_t)255;
        return p;
    };
    float* nxyz1  = (float*)alloc((size_t)32 * 256 * 3 * 4);
    float* feats1 = (float*)alloc((size_t)32 * 256 * 128 * 4);
    float* nxyz2  = (float*)alloc((size_t)32 * 64 * 3 * 4);
    float* feats2 = (float*)alloc((size_t)32 * 64 * 256 * 4);
    float* nxyz3  = (float*)alloc((size_t)32 * 16 * 3 * 4);
    float* feats3 = (float*)alloc((size_t)32 * 16 * 512 * 4);
    // pre-swizzled bf16 weight fragments
    unsigned short* w1as = (unsigned short*)alloc((size_t)4  * 1  * 64 * 8 * 2);  // stage1 W1 (9->32 x64)
    unsigned short* w1bs = (unsigned short*)alloc((size_t)8  * 2  * 64 * 8 * 2);  // stage1 W2 (64x128)
    unsigned short* w2as = (unsigned short*)alloc((size_t)8  * 5  * 64 * 8 * 2);  // stage2 W1 (131->160 x128)
    unsigned short* w2bs = (unsigned short*)alloc((size_t)16 * 4  * 64 * 8 * 2);  // stage2 W2 (128x256)
    unsigned short* w3as = (unsigned short*)alloc((size_t)16 * 9  * 64 * 8 * 2);  // stage3 W1 (259->288 x256)
    unsigned short* w3bs = (unsigned short*)alloc((size_t)32 * 8  * 64 * 8 * 2);  // stage3 W2 (256x512)
    unsigned short* w4as = (unsigned short*)alloc((size_t)32 * 17 * 64 * 8 * 2);  // head W1 (515->544 x512)
    unsigned short* w4bs = (unsigned short*)alloc((size_t)64 * 16 * 64 * 8 * 2);  // head W2 (512x1024)

    const float r2a = (float)(0.1 * 0.1);
    const float r2b = (float)(0.2 * 0.2);
    const float r2c = (float)(0.4 * 0.4);

    // ---- FPS (blocks 0-31) + weight pre-swizzle (blocks 32-159), one launch ----
    fps_wswz_kernel<<<160, 256, 0, stream>>>(pc, nxyz1, nxyz2, nxyz3,
                                             w1a, w1as, w1b, w1bs, w2a, w2as, w2b, w2bs,
                                             w3a, w3as, w3b, w3bs, w4a, w4as, w4b, w4bs);

    // ---- SA MLPs: full MFMA with inline ball query (no separate bq launch) ----
    sa_mlp_mfma_kernel<64, 9, 64, 128, 4096, 0><<<32 * 256, 256, 0, stream>>>(
        pc, pc, nxyz1, r2a, w1as, b1a, w1bs, b1b, feats1, 256);
    sa_mlp_mfma_kernel<64, 131, 128, 256, 256, 1><<<32 * 64, 256, 0, stream>>>(
        nxyz1, feats1, nxyz2, r2b, w2as, b2a, w2bs, b2b, feats2, 64);
    sa_mlp_mfma_kernel<32, 259, 256, 512, 64, 1><<<32 * 16, 256, 0, stream>>>(
        nxyz2, feats2, nxyz3, r2c, w3as, b3a, w3bs, b3b, feats3, 16);

    // ---- Head: full-MFMA MLP + fused maxpool(16) + fc1/fc2/bn, one launch ----
    sa_mlp_mfma_kernel<16, 515, 512, 1024, 16, 2><<<32, 256, 0, stream>>>(
        nxyz3, feats3, nullptr, 0.f, w4as, b4a, w4bs, b4b, out, 1,
        fc1w, fc1b, fc2w, fc2b, gam, bet);
}

// Round 26
// 583.730 us; speedup vs baseline: 1.1551x; 1.1551x over previous
//
#include <hip/hip_runtime.h>

#define DEV static __device__ __forceinline__

using bf16x8 = __attribute__((ext_vector_type(8))) short;   // 8 bf16 (4 VGPRs)
using f32x4  = __attribute__((ext_vector_type(4))) float;

DEV float sqdist(float dx, float dy, float dz) {
    // ((dx*dx + dy*dy) + dz*dz) with no FMA contraction — must match numpy f32
    return __fadd_rn(__fadd_rn(__fmul_rn(dx, dx), __fmul_rn(dy, dy)), __fmul_rn(dz, dz));
}

DEV void fma4(float4& acc, float h, const float4& w) {
    acc.x = fmaf(h, w.x, acc.x); acc.y = fmaf(h, w.y, acc.y);
    acc.z = fmaf(h, w.z, acc.z); acc.w = fmaf(h, w.w, acc.w);
}

DEV unsigned short f2bf_rne(float f) {   // fp32 -> bf16, round-nearest-even
    unsigned u = __builtin_bit_cast(unsigned, f);
    return (unsigned short)((u + 0x7FFFu + ((u >> 16) & 1u)) >> 16);
}

// ---- weight pre-swizzle section: fp32 W[K][C] -> bf16 fragment layout ----
// out[((nt*KB+kb)*64+lane)*8 + j] = bf16(W[kb*32+(lane>>4)*8+j][nt*16+(lane&15)])
template<int KSRC, int KB, int C>
DEV void wswz_sec(const float* __restrict__ W, unsigned short* __restrict__ out,
                  int idx0, int stride)
{
    constexpr int NT = C / 16;
    constexpr int TOTAL = NT * KB * 64 * 8;
    for (int idx = idx0; idx < TOTAL; idx += stride) {
        const int j    = idx & 7;
        const int lane = (idx >> 3) & 63;
        const int fb   = idx >> 9;          // nt*KB + kb
        const int kb   = fb % KB, nt = fb / KB;
        const int k    = kb * 32 + (lane >> 4) * 8 + j;
        const int c    = nt * 16 + (lane & 15);
        const float v  = (k < KSRC) ? W[(size_t)k * C + c] : 0.f;
        out[idx] = f2bf_rne(v);
    }
}

// ---- argmax combine steps (value desc, index asc on ties) ----
template<int CTRL>
DEV int dpp_mov(int v) {
    return __builtin_amdgcn_update_dpp(v, v, CTRL, 0xF, 0xF, false);
}
template<int CTRL>
DEV void red_step_dpp(float& bv, int& bi) {
    float ov = __builtin_bit_cast(float, dpp_mov<CTRL>(__builtin_bit_cast(int, bv)));
    int   oi = dpp_mov<CTRL>(bi);
    if (ov > bv || (ov == bv && oi < bi)) { bv = ov; bi = oi; }
}
// full 64-lane argmax; result valid in lane 63
DEV void wave_argmax(float& bv, int& bi) {
    red_step_dpp<0xB1>(bv, bi);    // quad_perm xor 1
    red_step_dpp<0x4E>(bv, bi);    // quad_perm xor 2
    red_step_dpp<0x141>(bv, bi);   // row_half_mirror (xor 4)
    red_step_dpp<0x140>(bv, bi);   // row_mirror (xor 8)
    red_step_dpp<0x142>(bv, bi);   // row_bcast15
    red_step_dpp<0x143>(bv, bi);   // row_bcast31 -> lane 63 has full result
}

// ---- single-wave FPS over LDS points (no barriers) ----
template<int N, int NPOINT>
DEV void fps_wave64(const float4* pts, float* sout, int lane) {
    constexpr int K = (N + 63) / 64;
    float rx[K], ry[K], rz[K], d[K];
#pragma unroll
    for (int k = 0; k < K; ++k) {
        const float4 c = pts[lane + k * 64];
        rx[k] = c.x; ry[k] = c.y; rz[k] = c.z; d[k] = 1e10f;
    }
    const float4 c0 = pts[0];
    float cx = c0.x, cy = c0.y, cz = c0.z;
    for (int s = 0; s < NPOINT; ++s) {
        if (lane == 0) { sout[s * 3 + 0] = cx; sout[s * 3 + 1] = cy; sout[s * 3 + 2] = cz; }
        float bestv = -1.0f; int besti = 0x7fffffff;
#pragma unroll
        for (int k = 0; k < K; ++k) {
            float d2 = sqdist(rx[k] - cx, ry[k] - cy, rz[k] - cz);
            d[k] = fminf(d[k], d2);
            if (d[k] > bestv) { bestv = d[k]; besti = lane + k * 64; }
        }
        wave_argmax(bestv, besti);
        const int far = __builtin_amdgcn_readlane(besti, 63);
        const float4 c = pts[far];
        cx = c.x; cy = c.y; cz = c.z;
    }
}

// ---- FPS device body (all 3 stages, 4-wave measured-floor config) ----
DEV void fps_body(const float* __restrict__ pc, int b, int tid,
                  float* __restrict__ nxyz1, float* __restrict__ nxyz2,
                  float* __restrict__ nxyz3)
{
    constexpr int N1 = 4096, NP1 = 256, NP2 = 64, NP3 = 16, T = 256, NW = T / 64;
    constexpr int K = N1 / T;
    __shared__ float4 pxyz[N1];
    __shared__ float  sout1[NP1 * 3];
    __shared__ float  sout2[NP2 * 3];
    __shared__ float  sout3[NP3 * 3];
    __shared__ float  rv[2][NW];
    __shared__ int    ri[2][NW];

    const int w = tid >> 6, lane = tid & 63;
    const float* base = pc + (size_t)b * N1 * 6;

    float rx[K], ry[K], rz[K], d[K];
#pragma unroll
    for (int k = 0; k < K; ++k) {
        const int p = tid + k * T;
        const float x = base[p * 6 + 0];
        const float y = base[p * 6 + 1];
        const float z = base[p * 6 + 2];
        pxyz[p] = make_float4(x, y, z, 0.f);
        rx[k] = x; ry[k] = y; rz[k] = z;
        d[k] = 1e10f;
    }
    __syncthreads();

    // ---- stage 1 ----
    {
        const float4 c0 = pxyz[0];
        float cx = c0.x, cy = c0.y, cz = c0.z;
        for (int s = 0; s < NP1; ++s) {
            if (tid == 0) { sout1[s * 3 + 0] = cx; sout1[s * 3 + 1] = cy; sout1[s * 3 + 2] = cz; }
            float bestv = -1.0f; int besti = 0x7fffffff;
#pragma unroll
            for (int k = 0; k < K; ++k) {
                float d2 = sqdist(rx[k] - cx, ry[k] - cy, rz[k] - cz);
                d[k] = fminf(d[k], d2);
                if (d[k] > bestv) { bestv = d[k]; besti = tid + k * T; }  // k asc => lowest p
            }
            wave_argmax(bestv, besti);

            const int par = s & 1;
            if (lane == 63) { rv[par][w] = bestv; ri[par][w] = besti; }
            __syncthreads();
            float bvv = rv[par][0]; int bii = ri[par][0];
#pragma unroll
            for (int q = 1; q < NW; ++q) {
                const float qv = rv[par][q]; const int qi = ri[par][q];
                if (qv > bvv || (qv == bvv && qi < bii)) { bvv = qv; bii = qi; }
            }
            const float4 c = pxyz[bii];
            cx = c.x; cy = c.y; cz = c.z;
        }
    }

    // ---- stages 2 + 3 on wave 0 ----
    if (w == 0) {
        for (int i = lane; i < NP1; i += 64)
            pxyz[i] = make_float4(sout1[i * 3 + 0], sout1[i * 3 + 1], sout1[i * 3 + 2], 0.f);
        fps_wave64<NP1, NP2>(pxyz, sout2, lane);
        for (int i = lane; i < NP2; i += 64)
            pxyz[i] = make_float4(sout2[i * 3 + 0], sout2[i * 3 + 1], sout2[i * 3 + 2], 0.f);
        fps_wave64<NP2, NP3>(pxyz, sout3, lane);
    }
    __syncthreads();

    float* o1 = nxyz1 + (size_t)b * NP1 * 3;
    for (int i = tid; i < NP1 * 3; i += T) o1[i] = sout1[i];
    float* o2 = nxyz2 + (size_t)b * NP2 * 3;
    if (tid < NP2 * 3) o2[tid] = sout2[tid];
    float* o3 = nxyz3 + (size_t)b * NP3 * 3;
    if (tid < NP3 * 3) o3[tid] = sout3[tid];
}

// ---- merged launch: blocks 0-31 run FPS; blocks 32-159 run weight swizzle ----
__global__ __launch_bounds__(256)
void fps_wswz_kernel(const float* __restrict__ pc,
                     float* __restrict__ nxyz1, float* __restrict__ nxyz2,
                     float* __restrict__ nxyz3,
                     const float* w1a, unsigned short* o1a,
                     const float* w1b, unsigned short* o1b,
                     const float* w2a, unsigned short* o2a,
                     const float* w2b, unsigned short* o2b,
                     const float* w3a, unsigned short* o3a,
                     const float* w3b, unsigned short* o3b,
                     const float* w4a, unsigned short* o4a,
                     const float* w4b, unsigned short* o4b)
{
    if (blockIdx.x < 32) {
        fps_body(pc, blockIdx.x, threadIdx.x, nxyz1, nxyz2, nxyz3);
    } else {
        const int idx0   = (blockIdx.x - 32) * 256 + threadIdx.x;
        const int stride = 128 * 256;
        wswz_sec<9,   1,  64 >(w1a, o1a, idx0, stride);
        wswz_sec<64,  2,  128>(w1b, o1b, idx0, stride);
        wswz_sec<131, 5,  128>(w2a, o2a, idx0, stride);
        wswz_sec<128, 4,  256>(w2b, o2b, idx0, stride);
        wswz_sec<259, 9,  256>(w3a, o3a, idx0, stride);
        wswz_sec<256, 8,  512>(w3b, o3b, idx0, stride);
        wswz_sec<515, 17, 512>(w4a, o4a, idx0, stride);
        wswz_sec<512, 16, 1024>(w4b, o4b, idx0, stride);
    }
}

// ---------------- Ball query (device body) -----------------
template<int N, int NSAMP, int STRIDE>
DEV void bq_dev(const float* __restrict__ xyz, const float* __restrict__ newxyz,
                int* __restrict__ gidx, float r2, int S, int total, int wid, int lane)
{
    if (wid >= total) return;
    const int b = wid / S;
    const float cx = newxyz[(size_t)wid * 3 + 0];
    const float cy = newxyz[(size_t)wid * 3 + 1];
    const float cz = newxyz[(size_t)wid * 3 + 2];
    const float* base = xyz + (size_t)b * N * STRIDE;
    int* out = gidx + (size_t)wid * NSAMP;

    int count = 0, first = N - 1;
    constexpr int NCH = (N + 63) / 64;
    for (int ch = 0; ch < NCH; ++ch) {
        int p = ch * 64 + lane;
        bool pred = false;
        if (N % 64 == 0 || p < N) {
            float dx = base[p * STRIDE + 0] - cx;
            float dy = base[p * STRIDE + 1] - cy;
            float dz = base[p * STRIDE + 2] - cz;
            pred = sqdist(dx, dy, dz) < r2;
        }
        unsigned long long m = __ballot(pred);
        if (m) {
            if (count == 0) first = ch * 64 + __builtin_ctzll(m);
            int pos = count + __popcll(m & ((1ull << lane) - 1ull));
            if (pred && pos < NSAMP) out[pos] = p;
            count += __popcll(m);
            if (count >= NSAMP) break;
        }
    }
    if (count > NSAMP) count = NSAMP;
    for (int pos = count + lane; pos < NSAMP; pos += 64) out[pos] = first;
}

// All three ball queries in one launch (block-range dispatch).
__global__ __launch_bounds__(256)
void bq_all_kernel(const float* __restrict__ pc,
                   const float* __restrict__ nxyz1, int* __restrict__ gidx1, float r2a,
                   const float* __restrict__ nxyz2, int* __restrict__ gidx2, float r2b,
                   const float* __restrict__ nxyz3, int* __restrict__ gidx3, float r2c)
{
    const int blk  = blockIdx.x;
    const int w    = threadIdx.x >> 6;
    const int lane = threadIdx.x & 63;
    if (blk < 2048) {
        bq_dev<4096, 64, 6>(pc, nxyz1, gidx1, r2a, 256, 32 * 256, blk * 4 + w, lane);
    } else if (blk < 2560) {
        bq_dev<256, 64, 3>(nxyz1, nxyz2, gidx2, r2b, 64, 32 * 64, (blk - 2048) * 4 + w, lane);
    } else {
        bq_dev<64, 32, 3>(nxyz2, nxyz3, gidx3, r2c, 16, 32 * 16, (blk - 2560) * 4 + w, lane);
    }
}

// ---------------- Grouped 2-layer MLP + maxpool, FULL MFMA ----
// Both layers on mfma_f32_16x16x32_bf16; W1s/W2s pre-swizzled bf16 fragments.
// MODE 0: stage1 gather (xyz stride 6, feats = pc permuted [3:6]++[0:3]).
// MODE 1: mid stages (xyz stride 3, feats array) via gidx.
// MODE 2: head — direct rows, fused maxpool, then fc1/fc2/bn in-block.
template<int NS, int CIN, int C1, int C2, int NSRC, int MODE>
__global__ __launch_bounds__(256)
void sa_mlp_mfma_kernel(const float* __restrict__ sxyz, const float* __restrict__ sfeat,
                        const float* __restrict__ newxyz, const int* __restrict__ gidx,
                        const unsigned short* __restrict__ W1s, const float* __restrict__ B1v,
                        const unsigned short* __restrict__ W2s, const float* __restrict__ B2v,
                        float* __restrict__ outf, int S,
                        const float* __restrict__ fc1w = nullptr, const float* __restrict__ fc1b = nullptr,
                        const float* __restrict__ fc2w = nullptr, const float* __restrict__ fc2b = nullptr,
                        const float* __restrict__ gamma = nullptr, const float* __restrict__ beta = nullptr)
{
    constexpr int T    = 256;
    constexpr int KP   = ((CIN + 31) / 32) * 32;   // K padded
    constexpr int LDXB = KP + 8;                   // bf16 x row stride (16B mult)
    constexpr int KBA  = KP / 32;                  // phase-A K-blocks
    constexpr int NMT  = NS / 16;                  // M-tiles
    constexpr int NTA  = C1 / 16 / 4;              // phase-A N-tiles per wave
    constexpr int LDHB = C1 + 8;                   // bf16 h1 row stride
    constexpr int KBB  = C1 / 32;                  // phase-B K-blocks
    constexpr int NTB  = C2 / 16 / 4;              // phase-B N-tiles per wave
    constexpr int CF   = CIN - 3;
    static_assert(NS % 16 == 0 && C1 % 64 == 0 && C2 % 64 == 0, "");

    __shared__ __align__(16) unsigned short xb[NS * LDXB];
    __shared__ __align__(16) unsigned short h1b[NS * LDHB];
    __shared__ int gix[NS];
    __shared__ float gmS[(MODE == 2) ? C2 : 4];    // fused-head: pooled features
    __shared__ float g1S[(MODE == 2) ? 1024 : 4];  // fused-head: fc1 output

    const int g   = blockIdx.x;
    const int b   = g / S;
    const int tid = threadIdx.x;
    const int w    = tid >> 6;
    const int lane = tid & 63;
    const int lr   = lane & 15;
    const int lg   = lane >> 4;

    float ctr0 = 0.f, ctr1 = 0.f, ctr2 = 0.f;
    if constexpr (MODE != 2) {
        ctr0 = newxyz[(size_t)g * 3 + 0];
        ctr1 = newxyz[(size_t)g * 3 + 1];
        ctr2 = newxyz[(size_t)g * 3 + 2];
        for (int i = tid; i < NS; i += T) gix[i] = gidx[(size_t)g * NS + i];
        __syncthreads();
    }

    // ---- gather full input as bf16 (rel-xyz in fp32, then RNE; pad = 0) ----
    for (int idx = tid; idx < NS * KP; idx += T) {
        const int p = idx / KP, k = idx - p * KP;
        float v = 0.f;
        if (k < CIN) {
            if constexpr (MODE == 2) {
                v = (k < 3) ? sxyz[((size_t)g * NS + p) * 3 + k]
                            : sfeat[((size_t)g * NS + p) * CF + (k - 3)];
            } else if constexpr (MODE == 0) {
                const int gi = gix[p];
                if (k < 3) {
                    const float c = (k == 0) ? ctr0 : ((k == 1) ? ctr1 : ctr2);
                    v = sxyz[((size_t)b * NSRC + gi) * 6 + k] - c;
                } else {
                    const int j2 = k - 3;   // feats = [pc[:,3:6], pc[:,0:3]]
                    v = sfeat[((size_t)b * NSRC + gi) * 6 + (j2 < 3 ? 3 + j2 : j2 - 3)];
                }
            } else {
                const int gi = gix[p];
                if (k < 3) {
                    const float c = (k == 0) ? ctr0 : ((k == 1) ? ctr1 : ctr2);
                    v = sxyz[((size_t)b * NSRC + gi) * 3 + k] - c;
                } else {
                    v = sfeat[((size_t)b * NSRC + gi) * CF + (k - 3)];
                }
            }
        }
        xb[(size_t)p * LDXB + k] = f2bf_rne(v);
    }
    __syncthreads();

    // ---- Phase A: h1 = relu(x @ W1 + b1) via MFMA ----
    {
        bf16x8 af[NMT][KBA];
#pragma unroll
        for (int mt = 0; mt < NMT; ++mt)
#pragma unroll
            for (int kb = 0; kb < KBA; ++kb)
                af[mt][kb] = *(const bf16x8*)&xb[(size_t)(mt * 16 + lr) * LDXB + kb * 32 + lg * 8];

#pragma unroll
        for (int q = 0; q < NTA; ++q) {
            const int nt = w * NTA + q;
            const int c  = nt * 16 + lr;
            bf16x8 bfr[KBA];
#pragma unroll
            for (int kb = 0; kb < KBA; ++kb)
                bfr[kb] = *(const bf16x8*)&W1s[(size_t)((nt * KBA + kb) * 64 + lane) * 8];
            const float bb = B1v[c];
#pragma unroll
            for (int mt = 0; mt < NMT; ++mt) {
                f32x4 ac = {bb, bb, bb, bb};
#pragma unroll
                for (int kb = 0; kb < KBA; ++kb)
                    ac = __builtin_amdgcn_mfma_f32_16x16x32_bf16(af[mt][kb], bfr[kb], ac, 0, 0, 0);
#pragma unroll
                for (int i = 0; i < 4; ++i) {
                    const int row = mt * 16 + lg * 4 + i;
                    h1b[(size_t)row * LDHB + c] = f2bf_rne(fmaxf(ac[i], 0.f));
                }
            }
        }
    }
    __syncthreads();

    // ---- Phase B: out = maxpool_p (h1 @ W2 + b2) via MFMA ----
    {
        bf16x8 af[NMT][KBB];
#pragma unroll
        for (int mt = 0; mt < NMT; ++mt)
#pragma unroll
            for (int kb = 0; kb < KBB; ++kb)
                af[mt][kb] = *(const bf16x8*)&h1b[(size_t)(mt * 16 + lr) * LDHB + kb * 32 + lg * 8];

#pragma unroll
        for (int q = 0; q < NTB; ++q) {
            const int nt = w * NTB + q;
            const int c  = nt * 16 + lr;
            bf16x8 bfr[KBB];
#pragma unroll
            for (int kb = 0; kb < KBB; ++kb)
                bfr[kb] = *(const bf16x8*)&W2s[(size_t)((nt * KBB + kb) * 64 + lane) * 8];
            const float bb = B2v[c];
            float colmax = 0.f;   // relu >= 0
#pragma unroll
            for (int mt = 0; mt < NMT; ++mt) {
                f32x4 ac = {bb, bb, bb, bb};
#pragma unroll
                for (int kb = 0; kb < KBB; ++kb)
                    ac = __builtin_amdgcn_mfma_f32_16x16x32_bf16(af[mt][kb], bfr[kb], ac, 0, 0, 0);
                float pm = fmaxf(fmaxf(ac[0], ac[1]), fmaxf(ac[2], ac[3]));
                pm = fmaxf(pm, __shfl_xor(pm, 16));
                pm = fmaxf(pm, __shfl_xor(pm, 32));
                colmax = fmaxf(colmax, pm);
            }
            if constexpr (MODE == 2) {
                if (lg == 0) gmS[c] = colmax;
            } else {
                if (lg == 0) outf[(size_t)g * C2 + c] = colmax;
            }
        }
    }

    // ---- fused head tail: fc1(relu) -> fc2 -> bn-ish (MODE 2 only) ----
    if constexpr (MODE == 2) {
        __syncthreads();
        {
            const int c0 = tid * 4;
            float4 a = *(const float4*)&fc1b[c0];
#pragma unroll 4
            for (int k = 0; k < 1024; ++k) {
                const float4 ww = *(const float4*)&fc1w[(size_t)k * 1024 + c0];
                fma4(a, gmS[k], ww);
            }
            g1S[c0 + 0] = fmaxf(a.x, 0.f); g1S[c0 + 1] = fmaxf(a.y, 0.f);
            g1S[c0 + 2] = fmaxf(a.z, 0.f); g1S[c0 + 3] = fmaxf(a.w, 0.f);
        }
        __syncthreads();
        if (tid < 128) {
            const float s = sqrtf(1.00001f);
            const int c = tid;
            float a = fc2b[c];
#pragma unroll 4
            for (int k = 0; k < 1024; ++k) a = fmaf(g1S[k], fc2w[(size_t)k * 128 + c], a);
            outf[(size_t)g * 128 + c] = (a / s) * gamma[c] + beta[c];
        }
    }
}

// ---------------------------------------------------------------------------
extern "C" void kernel_launch(void* const* d_in, const int* in_sizes, int n_in,
                              void* d_out, int out_size, void* d_ws, size_t ws_size,
                              hipStream_t stream)
{
    const float* pc   = (const float*)d_in[0];
    const float* w1a  = (const float*)d_in[1];  const float* b1a = (const float*)d_in[2];
    const float* w1b  = (const float*)d_in[3];  const float* b1b = (const float*)d_in[4];
    const float* w2a  = (const float*)d_in[5];  const float* b2a = (const float*)d_in[6];
    const float* w2b  = (const float*)d_in[7];  const float* b2b = (const float*)d_in[8];
    const float* w3a  = (const float*)d_in[9];  const float* b3a = (const float*)d_in[10];
    const float* w3b  = (const float*)d_in[11]; const float* b3b = (const float*)d_in[12];
    const float* w4a  = (const float*)d_in[13]; const float* b4a = (const float*)d_in[14];
    const float* w4b  = (const float*)d_in[15]; const float* b4b = (const float*)d_in[16];
    const float* fc1w = (const float*)d_in[17]; const float* fc1b = (const float*)d_in[18];
    const float* fc2w = (const float*)d_in[19]; const float* fc2b = (const float*)d_in[20];
    const float* gam  = (const float*)d_in[21]; const float* bet  = (const float*)d_in[22];
    float* out = (float*)d_out;

    char* ws = (char*)d_ws;
    size_t off = 0;
    auto alloc = [&](size_t bytes) -> void* {
        void* p = ws + off;
        off = (off + bytes + 255) & ~(size_t)255;
        return p;
    };
    float* nxyz1  = (float*)alloc((size_t)32 * 256 * 3 * 4);
    int*   gidx1  = (int*)  alloc((size_t)32 * 256 * 64 * 4);
    float* feats1 = (float*)alloc((size_t)32 * 256 * 128 * 4);
    float* nxyz2  = (float*)alloc((size_t)32 * 64 * 3 * 4);
    int*   gidx2  = (int*)  alloc((size_t)32 * 64 * 64 * 4);
    float* feats2 = (float*)alloc((size_t)32 * 64 * 256 * 4);
    float* nxyz3  = (float*)alloc((size_t)32 * 16 * 3 * 4);
    int*   gidx3  = (int*)  alloc((size_t)32 * 16 * 32 * 4);
    float* feats3 = (float*)alloc((size_t)32 * 16 * 512 * 4);
    // pre-swizzled bf16 weight fragments
    unsigned short* w1as = (unsigned short*)alloc((size_t)4  * 1  * 64 * 8 * 2);  // stage1 W1 (9->32 x64)
    unsigned short* w1bs = (unsigned short*)alloc((size_t)8  * 2  * 64 * 8 * 2);  // stage1 W2 (64x128)
    unsigned short* w2as = (unsigned short*)alloc((size_t)8  * 5  * 64 * 8 * 2);  // stage2 W1 (131->160 x128)
    unsigned short* w2bs = (unsigned short*)alloc((size_t)16 * 4  * 64 * 8 * 2);  // stage2 W2 (128x256)
    unsigned short* w3as = (unsigned short*)alloc((size_t)16 * 9  * 64 * 8 * 2);  // stage3 W1 (259->288 x256)
    unsigned short* w3bs = (unsigned short*)alloc((size_t)32 * 8  * 64 * 8 * 2);  // stage3 W2 (256x512)
    unsigned short* w4as = (unsigned short*)alloc((size_t)32 * 17 * 64 * 8 * 2);  // head W1 (515->544 x512)
    unsigned short* w4bs = (unsigned short*)alloc((size_t)64 * 16 * 64 * 8 * 2);  // head W2 (512x1024)

    const float r2a = (float)(0.1 * 0.1);
    const float r2b = (float)(0.2 * 0.2);
    const float r2c = (float)(0.4 * 0.4);

    // ---- FPS (blocks 0-31) + weight pre-swizzle (blocks 32-159), one launch ----
    fps_wswz_kernel<<<160, 256, 0, stream>>>(pc, nxyz1, nxyz2, nxyz3,
                                             w1a, w1as, w1b, w1bs, w2a, w2as, w2b, w2bs,
                                             w3a, w3as, w3b, w3bs, w4a, w4as, w4b, w4bs);

    // ---- All three ball queries: ONE launch (block-range dispatch) ----
    bq_all_kernel<<<2688, 256, 0, stream>>>(pc, nxyz1, gidx1, r2a,
                                            nxyz2, gidx2, r2b,
                                            nxyz3, gidx3, r2c);

    // ---- SA MLPs: all full MFMA ----
    sa_mlp_mfma_kernel<64, 9, 64, 128, 4096, 0><<<32 * 256, 256, 0, stream>>>(
        pc, pc, nxyz1, gidx1, w1as, b1a, w1bs, b1b, feats1, 256);
    sa_mlp_mfma_kernel<64, 131, 128, 256, 256, 1><<<32 * 64, 256, 0, stream>>>(
        nxyz1, feats1, nxyz2, gidx2, w2as, b2a, w2bs, b2b, feats2, 64);
    sa_mlp_mfma_kernel<32, 259, 256, 512, 64, 1><<<32 * 16, 256, 0, stream>>>(
        nxyz2, feats2, nxyz3, gidx3, w3as, b3a, w3bs, b3b, feats3, 16);

    // ---- Head: full-MFMA MLP + fused maxpool(16) + fc1/fc2/bn, one launch ----
    sa_mlp_mfma_kernel<16, 515, 512, 1024, 16, 2><<<32, 256, 0, stream>>>(
        nxyz3, feats3, nullptr, nullptr, w4as, b4a, w4bs, b4b, out, 1,
        fc1w, fc1b, fc2w, fc2b, gam, bet);
}